// Round 2
// baseline (367.668 us; speedup 1.0000x reference)
//
#include <hip/hip_runtime.h>

typedef __bf16 bf16x8 __attribute__((ext_vector_type(8)));
typedef short  s16x8  __attribute__((ext_vector_type(8)));
typedef float  f32x4  __attribute__((ext_vector_type(4)));

#define DEG2RAD     0.017453292519943295f
#define INV_P_NORM  (1.0f / 6.366468343804353f)
#define INV_TH_NORM (1.0f / 17.248858791583547f)
#define DTH_SCALE   2.8647889756541163f   /* 0.05*180/pi */

// ---- ws layout (bf16 elements) ----
// WT0 [256][32]  @ 0       (W0 4x256 transposed, K padded to 32 with zeros)
// WT1 [256][256] @ 8192
// WT2 [256][256] @ 73728
// WT3 [256][256] @ 139264
// WT4 [16][256]  @ 204800  (W4 256x16 transposed)
// total 208896 elems = 417792 bytes

static __device__ __forceinline__ unsigned short f2bf(float v) {
  unsigned int u = __builtin_bit_cast(unsigned int, v);
  u += 0x7fffu + ((u >> 16) & 1u);          // RNE
  return (unsigned short)(u >> 16);
}

__global__ void prep_kernel(const float* __restrict__ W0, const float* __restrict__ W1,
                            const float* __restrict__ W2, const float* __restrict__ W3,
                            const float* __restrict__ W4, unsigned short* __restrict__ ws) {
  int t = blockIdx.x * 256 + threadIdx.x;
  if (t < 8192) {
    int n = t >> 5, k = t & 31;
    ws[t] = f2bf(k < 4 ? W0[k * 256 + n] : 0.0f);
  } else if (t < 8192 + 3 * 65536) {
    int i = t - 8192;
    const float* W = (i < 65536) ? W1 : ((i < 131072) ? W2 : W3);
    int j = i & 65535, n = j >> 8, k = j & 255;
    ws[t] = f2bf(W[k * 256 + n]);
  } else if (t < 208896) {
    int i = t - (8192 + 3 * 65536);
    int n = i >> 8, k = i & 255;
    ws[t] = f2bf(W4[k * 16 + n]);
  }
}

// MFMA loop for one layer: out[128 x 256] partial per wave (128 rows x 64 cols),
// A from LDS hB, B (weights, pre-transposed WT[n][k]) direct from global/L2.
template <int KN, int KSTRIDE>
static __device__ __forceinline__ void layer_mfma(const unsigned short (*hB)[264],
                                                  const unsigned short* __restrict__ WT,
                                                  int c0, int l15, int lg,
                                                  f32x4 (&acc)[8][4]) {
  #pragma unroll
  for (int ks = 0; ks < KN; ++ks) {
    bf16x8 bf[4];
    #pragma unroll
    for (int n = 0; n < 4; ++n) {
      int col = c0 + n * 16 + l15;
      bf[n] = __builtin_bit_cast(bf16x8,
               *(const s16x8*)(WT + col * KSTRIDE + ks * 32 + lg * 8));
    }
    #pragma unroll
    for (int m = 0; m < 8; ++m) {
      bf16x8 af = __builtin_bit_cast(bf16x8,
                  *(const s16x8*)(&hB[m * 16 + l15][ks * 32 + lg * 8]));
      #pragma unroll
      for (int n = 0; n < 4; ++n)
        acc[m][n] = __builtin_amdgcn_mfma_f32_16x16x32_bf16(af, bf[n], acc[m][n], 0, 0, 0);
    }
  }
}

// relu(acc + bias) -> bf16 -> hB   (C/D layout: col = lane&15, row = (lane>>4)*4 + j)
static __device__ __forceinline__ void epilogue(unsigned short (*hB)[264],
                                                const float* __restrict__ bias,
                                                int c0, int l15, int lg,
                                                f32x4 (&acc)[8][4]) {
  #pragma unroll
  for (int n = 0; n < 4; ++n) {
    int col = c0 + n * 16 + l15;
    float bb = bias[col];
    #pragma unroll
    for (int m = 0; m < 8; ++m) {
      #pragma unroll
      for (int j = 0; j < 4; ++j) {
        float v = acc[m][n][j] + bb;
        v = v > 0.f ? v : 0.f;
        hB[m * 16 + lg * 4 + j][col] = f2bf(v);
      }
    }
  }
}

__global__ __launch_bounds__(256, 2) void taxi_kernel(
    const float* __restrict__ x, const unsigned short* __restrict__ ws,
    const float* __restrict__ b0, const float* __restrict__ b1,
    const float* __restrict__ b2, const float* __restrict__ b3,
    const float* __restrict__ b4,
    const float* __restrict__ W5, const float* __restrict__ b5,
    const float* __restrict__ W6, const float* __restrict__ b6,
    const float* __restrict__ W7, const float* __restrict__ b7,
    const float* __restrict__ W8, float* __restrict__ out) {
  __shared__ __align__(16) unsigned short hB[128][264];  // activations, bf16, +16B row pad
  __shared__ float h4s[128][17];                          // L4 output, fp32, +1 pad

  const int tid  = threadIdx.x;
  const int lane = tid & 63;
  const int wv   = tid >> 6;
  const int l15  = lane & 15;
  const int lg   = lane >> 4;
  const int c0   = wv * 64;
  const long r0  = (long)blockIdx.x * 128;

  const unsigned short* WT0 = ws;
  const unsigned short* WT1 = ws + 8192;
  const unsigned short* WT2 = ws + 73728;
  const unsigned short* WT3 = ws + 139264;
  const unsigned short* WT4 = ws + 204800;

  float p = 0.f, th = 0.f;
  if (tid < 128) {
    const float* xr = x + (r0 + tid) * 10;
    p  = xr[0];
    th = xr[1];
  }

  #pragma unroll 1
  for (int s = 0; s < 4; ++s) {
    // ---- stage input row [z0, z1, p/PN, th/THN] + zero k=4..31 ----
    if (tid < 128) {
      const float* xr = x + (r0 + tid) * 10;
      hB[tid][0] = f2bf(xr[2 + 2 * s]);
      hB[tid][1] = f2bf(xr[3 + 2 * s]);
      hB[tid][2] = f2bf(p * INV_P_NORM);
      hB[tid][3] = f2bf(th * INV_TH_NORM);
    }
    {
      int r = tid >> 1;
      unsigned int* pz = (unsigned int*)&hB[r][4 + 14 * (tid & 1)];
      #pragma unroll
      for (int i = 0; i < 7; ++i) pz[i] = 0u;
    }
    __syncthreads();

    // ---- L0: 4(->32 padded) -> 256, relu ----
    {
      f32x4 acc[8][4];
      #pragma unroll
      for (int m = 0; m < 8; ++m)
        #pragma unroll
        for (int n = 0; n < 4; ++n) acc[m][n] = f32x4{0.f, 0.f, 0.f, 0.f};
      layer_mfma<1, 32>(hB, WT0, c0, l15, lg, acc);
      __syncthreads();
      epilogue(hB, b0, c0, l15, lg, acc);
      __syncthreads();
    }
    // ---- L1..L3: 256 -> 256, relu ----
    {
      const unsigned short* WTs[3] = {WT1, WT2, WT3};
      const float* bs[3] = {b1, b2, b3};
      #pragma unroll 1
      for (int L = 0; L < 3; ++L) {
        f32x4 acc[8][4];
        #pragma unroll
        for (int m = 0; m < 8; ++m)
          #pragma unroll
          for (int n = 0; n < 4; ++n) acc[m][n] = f32x4{0.f, 0.f, 0.f, 0.f};
        layer_mfma<8, 256>(hB, WTs[L], c0, l15, lg, acc);
        __syncthreads();
        epilogue(hB, bs[L], c0, l15, lg, acc);
        __syncthreads();
      }
    }
    // ---- L4: 256 -> 16, relu (wave 0 only), fp32 result to h4s ----
    if (wv == 0) {
      f32x4 acc[8];
      #pragma unroll
      for (int m = 0; m < 8; ++m) acc[m] = f32x4{0.f, 0.f, 0.f, 0.f};
      #pragma unroll
      for (int ks = 0; ks < 8; ++ks) {
        bf16x8 bf = __builtin_bit_cast(bf16x8,
                    *(const s16x8*)(WT4 + l15 * 256 + ks * 32 + lg * 8));
        #pragma unroll
        for (int m = 0; m < 8; ++m) {
          bf16x8 af = __builtin_bit_cast(bf16x8,
                      *(const s16x8*)(&hB[m * 16 + l15][ks * 32 + lg * 8]));
          acc[m] = __builtin_amdgcn_mfma_f32_16x16x32_bf16(af, bf, acc[m], 0, 0, 0);
        }
      }
      float bb = b4[l15];
      #pragma unroll
      for (int m = 0; m < 8; ++m)
        #pragma unroll
        for (int j = 0; j < 4; ++j) {
          float v = acc[m][j] + bb;
          h4s[m * 16 + lg * 4 + j][l15] = v > 0.f ? v : 0.f;
        }
    }
    __syncthreads();

    // ---- per-row tail: L5..L8 fp32 + dynamics (threads 0..127) ----
    if (tid < 128) {
      float a5[8];
      #pragma unroll
      for (int j = 0; j < 8; ++j) {
        float acc5 = b5[j];
        #pragma unroll
        for (int i = 0; i < 16; ++i) acc5 += h4s[tid][i] * W5[i * 8 + j];
        a5[j] = acc5 > 0.f ? acc5 : 0.f;
      }
      float a6[8];
      #pragma unroll
      for (int j = 0; j < 8; ++j) {
        float acc6 = b6[j];
        #pragma unroll
        for (int i = 0; i < 8; ++i) acc6 += a5[i] * W6[i * 8 + j];
        a6[j] = acc6 > 0.f ? acc6 : 0.f;
      }
      float o0 = b7[0], o1 = b7[1];
      #pragma unroll
      for (int i = 0; i < 8; ++i) {
        o0 += a6[i] * W7[i * 2 + 0];
        o1 += a6[i] * W7[i * 2 + 1];
      }
      float u = o0 * W8[0] + o1 * W8[1];
      float ur = u * DEG2RAD;
      float dth = DTH_SCALE * (__sinf(ur) / __cosf(ur));
      #pragma unroll
      for (int it = 0; it < 20; ++it) {
        p += 0.25f * __sinf(th * DEG2RAD);
        th += dth;
      }
    }
    // next-iter staging is fenced by the __syncthreads() at loop top; hB's last
    // reader (wave0 L4 MFMA) completed before the post-L4 barrier above.
  }

  if (tid < 128) out[r0 + tid] = p;
}

extern "C" void kernel_launch(void* const* d_in, const int* in_sizes, int n_in,
                              void* d_out, int out_size, void* d_ws, size_t ws_size,
                              hipStream_t stream) {
  const float* x  = (const float*)d_in[0];
  const float* W0 = (const float*)d_in[1];
  const float* b0 = (const float*)d_in[2];
  const float* W1 = (const float*)d_in[3];
  const float* b1 = (const float*)d_in[4];
  const float* W2 = (const float*)d_in[5];
  const float* b2 = (const float*)d_in[6];
  const float* W3 = (const float*)d_in[7];
  const float* b3 = (const float*)d_in[8];
  const float* W4 = (const float*)d_in[9];
  const float* b4 = (const float*)d_in[10];
  const float* W5 = (const float*)d_in[11];
  const float* b5 = (const float*)d_in[12];
  const float* W6 = (const float*)d_in[13];
  const float* b6 = (const float*)d_in[14];
  const float* W7 = (const float*)d_in[15];
  const float* b7 = (const float*)d_in[16];
  const float* W8 = (const float*)d_in[17];
  float* out = (float*)d_out;
  unsigned short* ws = (unsigned short*)d_ws;

  int B = in_sizes[0] / 10;           // 131072
  int nblocks = B / 128;              // 1024

  prep_kernel<<<816, 256, 0, stream>>>(W0, W1, W2, W3, W4, ws);
  taxi_kernel<<<nblocks, 256, 0, stream>>>(x, ws, b0, b1, b2, b3, b4,
                                           W5, b5, W6, b6, W7, b7, W8, out);
}